// Round 17
// baseline (655.479 us; speedup 1.0000x reference)
//
#include <hip/hip_runtime.h>
#include <hip/hip_bf16.h>
#include <stdint.h>

typedef _Float16 f16x8 __attribute__((ext_vector_type(8)));
typedef float    f32x4 __attribute__((ext_vector_type(4)));

#define CIN   64
#define COUT  128
#define HH    128
#define WW    128
#define BB    8

#define TROW  130
#define ROWBYTES (130 * 128)
#define TSIZE ((size_t)BB * TROW * ROWBYTES)   // 17,305,600 B

#define LROWB (34 * 128)                  // 4352 B staged slice per trow
#define NCHKT (4 * 272)

#define AS1 __attribute__((address_space(1)))
#define AS3 __attribute__((address_space(3)))

// ---------------- pass 0: weights -> MFMA-A frag order + halo-row zeroing --------
__global__ void prep_plus(const float* __restrict__ wflat, _Float16* __restrict__ bp,
                          _Float16* __restrict__ T) {
    int gid = blockIdx.x * 256 + threadIdx.x;
    if (gid < 8 * 18 * 64 * 8) {
        int j = gid & 7;
        int l = (gid >> 3) & 63;
        int s = (gid >> 9) % 18;
        int n = gid / (18 * 512);
        int o = n * 16 + (l & 15);
        int c = ((s & 1) << 5) + ((l >> 4) << 3) + j;
        int k = s >> 1;
        bp[gid] = (_Float16)wflat[o * 576 + c * 9 + k];
        return;
    }
    int h = gid - 8 * 18 * 64 * 8;
    if (h < 16 * 1040) {
        int row = h / 1040, c = h - row * 1040;
        int b = row >> 1, yp = (row & 1) * 129;
        f16x8 z = {};
        *(f16x8*)((char*)T + (size_t)(b * TROW + yp) * ROWBYTES + c * 16) = z;
    }
}

// ---------------- pass 1: input f32 -> T f16 c-innermost swizzled ----------------
__global__ __launch_bounds__(256) void transpose_pass(const float* __restrict__ inp,
                                                      _Float16* __restrict__ T) {
    __shared__ float sT[64][129];
    const int b   = blockIdx.x >> 7;
    const int y   = blockIdx.x & 127;
    const int tid = threadIdx.x;

    const float* ib = inp + ((long)b * CIN * HH + y) * WW;
    const int xq = tid & 31, c8 = tid >> 5;
    #pragma unroll
    for (int i = 0; i < 8; ++i) {
        int c = c8 * 8 + i;
        float4 v = *(const float4*)(ib + (long)c * (HH * WW) + (xq << 2));
        *(float4*)&sT[c][xq << 2] = v;
    }
    __syncthreads();

    const int x  = tid & 127;
    const int ch = tid >> 7;
    char* rowp = (char*)T + (size_t)(b * TROW + y + 1) * ROWBYTES + (size_t)(x + 1) * 128;
    const int sw = (x + 1) & 7;
    for (int c0 = ch * 8; c0 < 64; c0 += 16) {
        f16x8 v;
        #pragma unroll
        for (int j = 0; j < 8; ++j) v[j] = (_Float16)sT[c0 + j][x];
        *(f16x8*)(rowp + (((c0 >> 3) ^ sw) << 4)) = v;
    }
    if (tid < 16) {
        char* basep = (char*)T + (size_t)(b * TROW + y + 1) * ROWBYTES
                    + ((tid >> 3) ? 129 * 128 : 0) + (tid & 7) * 16;
        f16x8 z = {};
        *(f16x8*)basep = z;
    }
}

// ---- pass 2 ABLATION FAMILY: exact R11 body, one phase stubbed per MODE ---------
// MODE 0 FULL | 1 NOSTAGE (skip DMA) | 2 NOLDS (const iv) | 3 NOMFMA (keepalive)
// | 4 NOSTORE (reduce+1 store). rep = blk>>11 (6 reps); rep>0 or MODE>0 -> wsout.
template<int MODE>
__global__ __launch_bounds__(256, 4) void depthcnn_abl(
    const _Float16* __restrict__ T, const float* __restrict__ gbuf,
    const float* __restrict__ bias, const _Float16* __restrict__ aprep,
    float* __restrict__ out, float* __restrict__ wsout)
{
    __shared__ __align__(1024) char sIn[4 * LROWB];
    __shared__ _Float16 sWf[2][9][36];

    const int blk    = blockIdx.x;
    const int rep    = blk >> 11;
    const int inner  = blk & 2047;
    const int b      = inner & 7;
    const int rest   = inner >> 3;
    const int strip  = rest & 63;
    const int xq     = rest >> 6;
    const int ystart = strip << 1;
    const int x0     = xq << 5;

    const int tid  = threadIdx.x;
    const int wave = tid >> 6;
    const int lane = tid & 63;
    const int oi   = wave;
    const int l15  = lane & 15;
    const int g4   = lane >> 4;

    if (MODE != 1) {   // ---- stage 4 trow slices via async DMA
        const char* Tb = (const char*)T + ((size_t)b * TROW + ystart) * ROWBYTES
                       + (size_t)x0 * 128;
        #pragma unroll
        for (int tt = 0; tt < 5; ++tt) {
            int t = tt * 256 + tid;
            if (t < NCHKT) {
                int tr = t / 272, c = t - tr * 272;
                __builtin_amdgcn_global_load_lds(
                    (const AS1 uint32_t*)(Tb + (size_t)tr * ROWBYTES + c * 16),
                    (AS3 uint32_t*)(sIn + tr * LROWB + c * 16), 16, 0, 0);
            }
        }
    }

    // ---- weight base pointers + tap-0 frags before the barrier
    const f16x8* __restrict__ ap = (const f16x8*)aprep;
    const char* wp0 = (const char*)ap + (size_t)((oi * 2 + 0) * 18) * 1024 + lane * 16;
    const char* wp1 = (const char*)ap + (size_t)((oi * 2 + 1) * 18) * 1024 + lane * 16;
    f16x8 af[2][2][2];
    af[0][0][0] = *(const f16x8*)(wp0);
    af[0][0][1] = *(const f16x8*)(wp0 + 1024);
    af[0][1][0] = *(const f16x8*)(wp1);
    af[0][1][1] = *(const f16x8*)(wp1 + 1024);

    // ---- wf for 2 rows x 32 px
    if (tid < 64) {
        const int r = tid >> 5, pxl = tid & 31, x = x0 + pxl, y = ystart + r;
        const float* g = gbuf + ((size_t)b * 2 + 1) * (HH * WW);
        float dc = 2.f * (g[y * WW + x] - 0.5f);
        float e[9];
        float ssum = 0.f;
        #pragma unroll
        for (int k = 0; k < 9; ++k) {
            int yy = y + (k / 3) - 1;
            int xx = x + (k % 3) - 1;
            float dn = 0.f;
            if ((unsigned)yy < 128u && (unsigned)xx < 128u)
                dn = 2.f * (g[yy * WW + xx] - 0.5f);
            float df = dn - dc;
            float ek = __expf(-df * df);
            e[k] = ek;
            ssum += ek;
        }
        float sc = 9.f / ssum;
        #pragma unroll
        for (int k = 0; k < 9; ++k) sWf[r][k][pxl] = (_Float16)(e[k] * sc);
    }

    __syncthreads();

    const char* bwf = (const char*)&sWf[0][0][0] + l15 * 2;

    // constant iv for NOLDS (register-resident, no LDS dependence)
    f16x8 ivc;
    #pragma unroll
    for (int j = 0; j < 8; ++j) ivc[j] = (_Float16)(((lane + j) & 15) * 0.0625f);

    const char* binA[3][2];
    #pragma unroll
    for (int d = 0; d < 3; ++d)
        #pragma unroll
        for (int ch = 0; ch < 2; ++ch)
            binA[d][ch] = sIn + (((l15 + d) << 7)
                        + ((((ch << 2) | g4) ^ ((l15 + d) & 7)) << 4));

    f32x4 acc[2][2][2];
    #pragma unroll
    for (int r = 0; r < 2; ++r)
        #pragma unroll
        for (int t2 = 0; t2 < 2; ++t2)
            #pragma unroll
            for (int pt = 0; pt < 2; ++pt)
                acc[r][t2][pt] = (f32x4){0.f, 0.f, 0.f, 0.f};

    #pragma unroll
    for (int k = 0; k < 9; ++k) {
        if (k < 8) {
            const char* q0 = wp0 + (k + 1) * 2048;
            const char* q1 = wp1 + (k + 1) * 2048;
            af[(k + 1) & 1][0][0] = *(const f16x8*)(q0);
            af[(k + 1) & 1][0][1] = *(const f16x8*)(q0 + 1024);
            af[(k + 1) & 1][1][0] = *(const f16x8*)(q1);
            af[(k + 1) & 1][1][1] = *(const f16x8*)(q1 + 1024);
        }
        const int dy = k / 3;
        const int dx = k - 3 * dy;
        #pragma unroll
        for (int r = 0; r < 2; ++r) {
            _Float16 wh[2];
            #pragma unroll
            for (int pt = 0; pt < 2; ++pt)
                wh[pt] = *(const _Float16*)(bwf + ((r * 9 + k) * 72 + pt * 32));
            #pragma unroll
            for (int ch = 0; ch < 2; ++ch) {
                f16x8 bf[2];
                #pragma unroll
                for (int pt = 0; pt < 2; ++pt) {
                    f16x8 iv;
                    if (MODE != 2)
                        iv = *(const f16x8*)(binA[dx][ch] + ((r + dy) * LROWB + (pt << 11)));
                    else
                        iv = ivc;
                    f16x8 w8 = {wh[pt], wh[pt], wh[pt], wh[pt],
                                wh[pt], wh[pt], wh[pt], wh[pt]};
                    bf[pt] = iv * w8;
                }
                if (MODE != 3) {
                    #pragma unroll
                    for (int t2 = 0; t2 < 2; ++t2)
                        #pragma unroll
                        for (int pt = 0; pt < 2; ++pt)
                            acc[r][t2][pt] = __builtin_amdgcn_mfma_f32_16x16x32_f16(
                                af[k & 1][t2][ch], bf[pt], acc[r][t2][pt], 0, 0, 0);
                } else {
                    // keep inputs live without MFMA (rule #17)
                    asm volatile("" :: "v"(bf[0]), "v"(bf[1]),
                                       "v"(af[k & 1][0][ch]), "v"(af[k & 1][1][ch]));
                }
            }
        }
    }

    float* obase = (MODE == 0 && rep == 0) ? out : wsout;
    float* ob = obase + (size_t)b * COUT * (HH * WW) + x0;

    if (MODE != 4) {
        #pragma unroll
        for (int r = 0; r < 2; ++r) {
            const int y = ystart + r;
            #pragma unroll
            for (int t2 = 0; t2 < 2; ++t2) {
                #pragma unroll
                for (int pt = 0; pt < 2; ++pt) {
                    #pragma unroll
                    for (int r4 = 0; r4 < 4; ++r4) {
                        const int o = (oi << 5) + (t2 << 4) + (g4 << 2) + r4;
                        ob[(size_t)o * (HH * WW) + (size_t)y * WW + (pt << 4) + l15]
                            = acc[r][t2][pt][r4] + bias[o];
                    }
                }
            }
        }
    } else {
        f32x4 s = acc[0][0][0] + acc[0][0][1] + acc[0][1][0] + acc[0][1][1]
                + acc[1][0][0] + acc[1][0][1] + acc[1][1][0] + acc[1][1][1];
        wsout[(size_t)blk * 256 + tid] = s[0] + s[1] + s[2] + s[3] + bias[lane];
    }
}

extern "C" void kernel_launch(void* const* d_in, const int* in_sizes, int n_in,
                              void* d_out, int out_size, void* d_ws, size_t ws_size,
                              hipStream_t stream) {
    const float* inp  = (const float*)d_in[0];
    const float* gbuf = (const float*)d_in[1];
    const float* wts  = (const float*)d_in[2];
    const float* bias = (const float*)d_in[3];

    _Float16* T  = (_Float16*)d_ws;                     // 17,305,600 B
    _Float16* bp = (_Float16*)((char*)d_ws + TSIZE);    // +147,456 B
    float*    mw = (float*)((char*)d_ws + (size_t)(32u << 20));   // 67MB mirror

    hipLaunchKernelGGL(prep_plus, dim3(353), dim3(256), 0, stream, wts, bp, T);
    hipLaunchKernelGGL(transpose_pass, dim3(BB * HH), dim3(256), 0, stream, inp, T);

    const dim3 G(2048 * 6), Blk(256);
    hipLaunchKernelGGL((depthcnn_abl<0>), G, Blk, 0, stream, T, gbuf, bias, bp, (float*)d_out, mw);
    hipLaunchKernelGGL((depthcnn_abl<1>), G, Blk, 0, stream, T, gbuf, bias, bp, (float*)d_out, mw);
    hipLaunchKernelGGL((depthcnn_abl<2>), G, Blk, 0, stream, T, gbuf, bias, bp, (float*)d_out, mw);
    hipLaunchKernelGGL((depthcnn_abl<3>), G, Blk, 0, stream, T, gbuf, bias, bp, (float*)d_out, mw);
    hipLaunchKernelGGL((depthcnn_abl<4>), G, Blk, 0, stream, T, gbuf, bias, bp, (float*)d_out, mw);
}

// Round 18
// 49.232 us; speedup vs baseline: 13.3141x; 13.3141x over previous
//
#include <hip/hip_runtime.h>
#include <hip/hip_bf16.h>
#include <stdint.h>

typedef _Float16 f16x8 __attribute__((ext_vector_type(8)));
typedef float    f32x4 __attribute__((ext_vector_type(4)));

#define CIN   64
#define COUT  128
#define HH    128
#define WW    128
#define BB    8

#define TROW  130                         // y' rows per batch (halo rows 0,129 zero)
#define ROWBYTES (130 * 128)              // 16640 B per (b,y') row: 130 x' * 64c * 2B
#define TSIZE ((size_t)BB * TROW * ROWBYTES)   // 17,305,600 B

#define LROWB (34 * 128)                  // 4352 B: staged 34-col slice of one trow
#define NCHKT (4 * 272)                   // total 16B chunks staged (4 trows x 272)

#define AS1 __attribute__((address_space(1)))
#define AS3 __attribute__((address_space(3)))

// T row byte layout (f16, c-innermost, XOR-swizzled 16B slots):
//   byte(x', c) = x'*128 + (((c>>3) ^ (x'&7)) << 4) + (c&7)*2

// ---------------- pass 0: weights -> MFMA-A frag order, DX-MAJOR tap order -------
// Tap order k' = dx*3 + dy (so the main loop can cache input rows per dx).
// frag[((ot*18 + s')*64 + lane)*8 + j] = W2[ot*16+(l&15)][c*9 + k],
//   k' = s'>>1; dx = k'/3; dy = k'%3; k = dy*3+dx;
//   c  = (s'&1)*32 + ((l>>4)&3)*8 + j
__global__ void prep_plus(const float* __restrict__ wflat, _Float16* __restrict__ bp,
                          _Float16* __restrict__ T) {
    int gid = blockIdx.x * 256 + threadIdx.x;
    if (gid < 8 * 18 * 64 * 8) {
        int j  = gid & 7;
        int l  = (gid >> 3) & 63;
        int sp = (gid >> 9) % 18;
        int n  = gid / (18 * 512);
        int o  = n * 16 + (l & 15);
        int kp = sp >> 1;
        int dx = kp / 3, dy = kp - 3 * dx;
        int k  = dy * 3 + dx;
        int c  = ((sp & 1) << 5) + ((l >> 4) << 3) + j;
        bp[gid] = (_Float16)wflat[o * 576 + c * 9 + k];
        return;
    }
    int h = gid - 8 * 18 * 64 * 8;
    if (h < 16 * 1040) {                  // zero halo rows y'=0,129 of each batch
        int row = h / 1040, c = h - row * 1040;
        int b = row >> 1, yp = (row & 1) * 129;
        f16x8 z = {};
        *(f16x8*)((char*)T + (size_t)(b * TROW + yp) * ROWBYTES + c * 16) = z;
    }
}

// ---------------- pass 1: input f32 -> T f16, swizzled; XCD-AFFINE (b = blk&7) ---
__global__ __launch_bounds__(256) void transpose_pass(const float* __restrict__ inp,
                                                      _Float16* __restrict__ T) {
    __shared__ float sT[64][129];
    const int b   = blockIdx.x & 7;        // same XCD pinning as the main kernel
    const int y   = blockIdx.x >> 3;
    const int tid = threadIdx.x;

    const float* ib = inp + ((long)b * CIN * HH + y) * WW;
    const int xq = tid & 31, c8 = tid >> 5;
    #pragma unroll
    for (int i = 0; i < 8; ++i) {
        int c = c8 * 8 + i;
        float4 v = *(const float4*)(ib + (long)c * (HH * WW) + (xq << 2));
        *(float4*)&sT[c][xq << 2] = v;
    }
    __syncthreads();

    const int x  = tid & 127;
    const int ch = tid >> 7;
    char* rowp = (char*)T + (size_t)(b * TROW + y + 1) * ROWBYTES + (size_t)(x + 1) * 128;
    const int sw = (x + 1) & 7;
    for (int c0 = ch * 8; c0 < 64; c0 += 16) {
        f16x8 v;
        #pragma unroll
        for (int j = 0; j < 8; ++j) v[j] = (_Float16)sT[c0 + j][x];
        *(f16x8*)(rowp + (((c0 >> 3) ^ sw) << 4)) = v;
    }
    if (tid < 16) {   // zero col halos x'=0, x'=129
        char* basep = (char*)T + (size_t)(b * TROW + y + 1) * ROWBYTES
                    + ((tid >> 3) ? 129 * 128 : 0) + (tid & 7) * 16;
        f16x8 z = {};
        *(f16x8*)basep = z;
    }
}

// ---- pass 2: main — block = (b, 2-row strip, 32-px quarter), all 128 o ----------
// R11 base + (1) dx-major K-order with iv[4][2][2] register cache: 48 ds_reads
// per wave (was 72); (2) 3 blocks/CU residency -> 2.7 dispatch rounds so staging
// of later rounds pipelines under compute of earlier ones; (3) weights streamed
// in the SAME dx-major order (prep packs them so) via af[2][2][2] double buffer.
__global__ __launch_bounds__(256, 3) void depthcnn_main(
    const _Float16* __restrict__ T, const float* __restrict__ gbuf,
    const float* __restrict__ bias, const _Float16* __restrict__ aprep,
    float* __restrict__ out)
{
    __shared__ __align__(1024) char sIn[4 * LROWB];      // 17,408 B: 4 trow slices
    __shared__ _Float16 sWf[2][9][36];                   // 1,296 B -> 18,704 total

    const int blk    = blockIdx.x;
    const int b      = blk & 7;            // XCD-pinned: batch b -> XCD b
    const int rest   = blk >> 3;
    const int strip  = rest & 63;          // 2-row strip
    const int xq     = rest >> 6;          // 32-px quarter (0..3)
    const int ystart = strip << 1;
    const int x0     = xq << 5;

    const int tid  = threadIdx.x;
    const int wave = tid >> 6;             // oi 0..3
    const int lane = tid & 63;
    const int oi   = wave;
    const int l15  = lane & 15;
    const int g4   = lane >> 4;

    // ---- stage 4 trow slices (ystart..ystart+3) x 34 cols via async DMA
    {
        const char* Tb = (const char*)T + ((size_t)b * TROW + ystart) * ROWBYTES
                       + (size_t)x0 * 128;
        #pragma unroll
        for (int tt = 0; tt < 5; ++tt) {
            int t = tt * 256 + tid;
            if (t < NCHKT) {
                int tr = t / 272, c = t - tr * 272;
                __builtin_amdgcn_global_load_lds(
                    (const AS1 uint32_t*)(Tb + (size_t)tr * ROWBYTES + c * 16),
                    (AS3 uint32_t*)(sIn + tr * LROWB + c * 16), 16, 0, 0);
            }
        }
    }

    // ---- weight base pointers + step-0 frags (dx-major order) before the barrier
    const f16x8* __restrict__ ap = (const f16x8*)aprep;
    const char* wp0 = (const char*)ap + (size_t)((oi * 2 + 0) * 18) * 1024 + lane * 16;
    const char* wp1 = (const char*)ap + (size_t)((oi * 2 + 1) * 18) * 1024 + lane * 16;
    f16x8 af[2][2][2];                     // [parity][t2][ch]
    af[0][0][0] = *(const f16x8*)(wp0);
    af[0][0][1] = *(const f16x8*)(wp0 + 1024);
    af[0][1][0] = *(const f16x8*)(wp1);
    af[0][1][1] = *(const f16x8*)(wp1 + 1024);

    // ---- wf for 2 rows x 32 px — spread over 16 lanes of every wave
    if (g4 == 0) {
        const int item = (wave << 4) | l15;   // 0..63
        const int r = item >> 5, pxl = item & 31, x = x0 + pxl, y = ystart + r;
        const float* g = gbuf + ((size_t)b * 2 + 1) * (HH * WW);
        float dc = 2.f * (g[y * WW + x] - 0.5f);
        float e[9];
        float ssum = 0.f;
        #pragma unroll
        for (int k = 0; k < 9; ++k) {
            int yy = y + (k / 3) - 1;
            int xx = x + (k % 3) - 1;
            float dn = 0.f;
            if ((unsigned)yy < 128u && (unsigned)xx < 128u)
                dn = 2.f * (g[yy * WW + xx] - 0.5f);
            float df = dn - dc;
            float ek = __expf(-df * df);
            e[k] = ek;
            ssum += ek;
        }
        float sc = 9.f / ssum;
        #pragma unroll
        for (int k = 0; k < 9; ++k) sWf[r][k][pxl] = (_Float16)(e[k] * sc);
    }

    __syncthreads();   // ONE barrier: DMA stage + wf writes visible

    const char* bwf = (const char*)&sWf[0][0][0] + l15 * 2;   // +(r*9+k)*72+pt*32

    // swizzled LDS bases per (dx, ch)
    const char* binA[3][2];
    #pragma unroll
    for (int d = 0; d < 3; ++d)
        #pragma unroll
        for (int ch = 0; ch < 2; ++ch)
            binA[d][ch] = sIn + (((l15 + d) << 7)
                        + ((((ch << 2) | g4) ^ ((l15 + d) & 7)) << 4));

    f32x4 acc[2][2][2];   // [row][t2][pt]
    #pragma unroll
    for (int r = 0; r < 2; ++r)
        #pragma unroll
        for (int t2 = 0; t2 < 2; ++t2)
            #pragma unroll
            for (int pt = 0; pt < 2; ++pt)
                acc[r][t2][pt] = (f32x4){0.f, 0.f, 0.f, 0.f};

    #pragma unroll
    for (int dxi = 0; dxi < 3; ++dxi) {
        // dx-batch input cache: 4 trows x 2 ch x 2 pt = 16 ds_read_b128 (64 VGPR)
        f16x8 iv[4][2][2];
        #pragma unroll
        for (int t = 0; t < 4; ++t)
            #pragma unroll
            for (int ch = 0; ch < 2; ++ch)
                #pragma unroll
                for (int pt = 0; pt < 2; ++pt)
                    iv[t][ch][pt] = *(const f16x8*)(binA[dxi][ch]
                                  + (t * LROWB + (pt << 11)));
        #pragma unroll
        for (int dyi = 0; dyi < 3; ++dyi) {
            const int kp = dxi * 3 + dyi;         // streaming index (dx-major)
            const int k  = dyi * 3 + dxi;         // actual tap (for wf)
            if (kp < 8) {   // prefetch next step's weight frags (linear in kp)
                const char* q0 = wp0 + (kp + 1) * 2048;
                const char* q1 = wp1 + (kp + 1) * 2048;
                af[(kp + 1) & 1][0][0] = *(const f16x8*)(q0);
                af[(kp + 1) & 1][0][1] = *(const f16x8*)(q0 + 1024);
                af[(kp + 1) & 1][1][0] = *(const f16x8*)(q1);
                af[(kp + 1) & 1][1][1] = *(const f16x8*)(q1 + 1024);
            }
            #pragma unroll
            for (int r = 0; r < 2; ++r) {
                _Float16 wh[2];
                #pragma unroll
                for (int pt = 0; pt < 2; ++pt)
                    wh[pt] = *(const _Float16*)(bwf + ((r * 9 + k) * 72 + pt * 32));
                #pragma unroll
                for (int ch = 0; ch < 2; ++ch) {
                    f16x8 bf[2];
                    #pragma unroll
                    for (int pt = 0; pt < 2; ++pt) {
                        f16x8 w8 = {wh[pt], wh[pt], wh[pt], wh[pt],
                                    wh[pt], wh[pt], wh[pt], wh[pt]};
                        bf[pt] = iv[r + dyi][ch][pt] * w8;
                    }
                    #pragma unroll
                    for (int t2 = 0; t2 < 2; ++t2)
                        #pragma unroll
                        for (int pt = 0; pt < 2; ++pt)
                            acc[r][t2][pt] = __builtin_amdgcn_mfma_f32_16x16x32_f16(
                                af[kp & 1][t2][ch], bf[pt], acc[r][t2][pt], 0, 0, 0);
                }
            }
        }
    }

    // ---- epilogue: D row = o (g4*4+r4), col = px (l15) -> full 64B lines
    float* ob = out + (size_t)b * COUT * (HH * WW) + x0;
    #pragma unroll
    for (int r = 0; r < 2; ++r) {
        const int y = ystart + r;
        #pragma unroll
        for (int t2 = 0; t2 < 2; ++t2) {
            #pragma unroll
            for (int pt = 0; pt < 2; ++pt) {
                #pragma unroll
                for (int r4 = 0; r4 < 4; ++r4) {
                    const int o = (oi << 5) + (t2 << 4) + (g4 << 2) + r4;
                    ob[(size_t)o * (HH * WW) + (size_t)y * WW + (pt << 4) + l15]
                        = acc[r][t2][pt][r4] + bias[o];
                }
            }
        }
    }
}

extern "C" void kernel_launch(void* const* d_in, const int* in_sizes, int n_in,
                              void* d_out, int out_size, void* d_ws, size_t ws_size,
                              hipStream_t stream) {
    const float* inp  = (const float*)d_in[0];
    const float* gbuf = (const float*)d_in[1];
    const float* wts  = (const float*)d_in[2];
    const float* bias = (const float*)d_in[3];

    _Float16* T  = (_Float16*)d_ws;                     // 17,305,600 B
    _Float16* bp = (_Float16*)((char*)d_ws + TSIZE);    // +147,456 B

    hipLaunchKernelGGL(prep_plus, dim3(353), dim3(256), 0, stream, wts, bp, T);
    hipLaunchKernelGGL(transpose_pass, dim3(BB * HH), dim3(256), 0, stream, inp, T);
    hipLaunchKernelGGL(depthcnn_main, dim3(2048), dim3(256), 0, stream,
                       T, gbuf, bias, bp, (float*)d_out);
}